// Round 8
// baseline (704.968 us; speedup 1.0000x reference)
//
#include <hip/hip_runtime.h>

// Batched 8x8 iDCT: out = M^T * img * M + 128
//   M[i][j] = 0.5 * a[i] * cos((2j+1)*i*pi/16)
//   a[i]    = alpha[i*8+1]       (alpha = outer(a,a), a[1]==1)
//   cos term = dct[i*512 + j*8]  (dct_tensor[i,0,j,0]; cos(0)==1)
//
// Design H: barrier-free row-per-lane, persistent grid, 1-deep prefetch.
//   - lane owns one row of each of its 2 blocks; all global ops 2x dwordx4/block,
//     lanes stride 32B -> fully coalesced
//   - P-exchange is INTRA-WAVE (lane t writes block t>>3; only lanes with same
//     t>>3 read it) -> no __syncthreads. DS ops of a wave execute in order;
//     a wave-local s_waitcnt lgkmcnt(0) + compiler memory fences suffice.
//   - persistent 2048 WGs, next tile's 4 loads issued before current compute
//     -> HBM requests always in flight (no WG-barrier drain, no WG churn)
//   - M in SGPRs via v_readlane; P in LDS stride-17-float4 (conflict-free)
//   - plain stores (NT stores proven harmful in R6: FETCH 996MB, WRITE 640MB)

#define WG      256
#define BPW     32                  // blocks per set (WG/8)
#define SETS    2
#define BLKWG   (SETS * BPW)        // 64 blocks per tile
#define STRIDE4 17                  // float4 stride per block in LDS
#define MAXWG   2048

__global__ __launch_bounds__(WG, 8) void dct8x8_kernel(
    const float* __restrict__ image,
    const float* __restrict__ alpha,
    const float* __restrict__ dct,
    float* __restrict__ out,
    int nblocks)
{
    __shared__ float4 lds4[SETS * BPW * STRIDE4];   // 17408 B

    const int t = threadIdx.x;
    const int b = t >> 3;          // local block within a set (0..31)
    const int r = t & 7;           // my row
    const int lane = t & 63;

    // ---- M -> SGPRs: one element per lane, readlane-broadcast ----
    float mv;
    {
        const int i = lane >> 3, j = lane & 7;
        mv = 0.5f * alpha[i * 8 + 1] * dct[i * 512 + j * 8];
    }
    float M[64];
#pragma unroll
    for (int k = 0; k < 64; ++k)
        M[k] = __int_as_float(__builtin_amdgcn_readlane(__float_as_int(mv), k));

    // ---- stage-2 weights M[x][r] (runtime r): per-lane loads, L1-hit ----
    float mu[8];
#pragma unroll
    for (int x = 0; x < 8; ++x)
        mu[x] = 0.5f * alpha[x * 8 + 1] * dct[x * 512 + r * 8];

    const float4* __restrict__ in4 = (const float4*)image;
    float4* __restrict__ o4 = (float4*)out;

    const long long ntiles = ((long long)nblocks + BLKWG - 1) / BLKWG;
    long long tile = blockIdx.x;
    if (tile >= ntiles) return;

    // ---- prologue: load tile0 (4 dwordx4 in flight) ----
    float4 c0lo = make_float4(0.f,0.f,0.f,0.f), c0hi = c0lo, c1lo = c0lo, c1hi = c0lo;
    {
        const long long g0 = tile * BLKWG + b;
        const long long g1 = g0 + BPW;
        if (g0 < nblocks) { const size_t p = (size_t)g0 * 16 + r * 2; c0lo = in4[p]; c0hi = in4[p+1]; }
        if (g1 < nblocks) { const size_t p = (size_t)g1 * 16 + r * 2; c1lo = in4[p]; c1hi = in4[p+1]; }
    }

    while (true) {
        // ---- prefetch next tile (stays in flight through compute+exchange) ----
        const long long nxt = tile + gridDim.x;
        const bool have_nxt = nxt < ntiles;
        float4 n0lo = make_float4(0.f,0.f,0.f,0.f), n0hi = n0lo, n1lo = n0lo, n1hi = n0lo;
        if (have_nxt) {
            const long long g0 = nxt * BLKWG + b;
            const long long g1 = g0 + BPW;
            if (g0 < nblocks) { const size_t p = (size_t)g0 * 16 + r * 2; n0lo = in4[p]; n0hi = in4[p+1]; }
            if (g1 < nblocks) { const size_t p = (size_t)g1 * 16 + r * 2; n1lo = in4[p]; n1hi = in4[p+1]; }
        }

        // ---- stage 1 (both sets): P[v] = sum_y row[y]*M[y][v] -> LDS ----
#pragma unroll
        for (int s = 0; s < SETS; ++s) {
            const float4 vlo = s ? c1lo : c0lo;
            const float4 vhi = s ? c1hi : c0hi;
            const float row[8] = {vlo.x, vlo.y, vlo.z, vlo.w,
                                  vhi.x, vhi.y, vhi.z, vhi.w};
            float P[8];
#pragma unroll
            for (int v = 0; v < 8; ++v) {
                float acc = 0.0f;
#pragma unroll
                for (int y = 0; y < 8; ++y)
                    acc = fmaf(row[y], M[y * 8 + v], acc);
                P[v] = acc;
            }
            float4* buf = &lds4[s * (BPW * STRIDE4)];
            buf[b * STRIDE4 + r * 2 + 0] = make_float4(P[0], P[1], P[2], P[3]);
            buf[b * STRIDE4 + r * 2 + 1] = make_float4(P[4], P[5], P[6], P[7]);
        }

        // wave-local: wait for MY wave's ds_writes to commit (intra-wave exchange,
        // DS ops of a wave are processed in order -> no WG barrier needed)
        asm volatile("s_waitcnt lgkmcnt(0)" ::: "memory");

        // ---- stage 2 (both sets): O[v] = 128 + sum_x mu[x]*P[x][v]; store ----
#pragma unroll
        for (int s = 0; s < SETS; ++s) {
            const float4* buf = &lds4[s * (BPW * STRIDE4)];
            float O[8] = {128.f,128.f,128.f,128.f,128.f,128.f,128.f,128.f};
#pragma unroll
            for (int x = 0; x < 8; ++x) {
                const float4 plo = buf[b * STRIDE4 + x * 2 + 0];
                const float4 phi = buf[b * STRIDE4 + x * 2 + 1];
                const float m = mu[x];
                O[0] = fmaf(m, plo.x, O[0]);
                O[1] = fmaf(m, plo.y, O[1]);
                O[2] = fmaf(m, plo.z, O[2]);
                O[3] = fmaf(m, plo.w, O[3]);
                O[4] = fmaf(m, phi.x, O[4]);
                O[5] = fmaf(m, phi.y, O[5]);
                O[6] = fmaf(m, phi.z, O[6]);
                O[7] = fmaf(m, phi.w, O[7]);
            }
            const long long gblk = tile * BLKWG + s * BPW + b;
            if (gblk < nblocks) {
                const size_t p = (size_t)gblk * 16 + r * 2;
                o4[p]     = make_float4(O[0], O[1], O[2], O[3]);
                o4[p + 1] = make_float4(O[4], O[5], O[6], O[7]);
            }
        }

        // compiler fence: next iteration's ds_writes must not hoist above
        // this iteration's ds_reads (HW keeps per-wave DS order)
        asm volatile("" ::: "memory");

        if (!have_nxt) break;
        c0lo = n0lo; c0hi = n0hi; c1lo = n1lo; c1hi = n1hi;
        tile = nxt;
    }
}

extern "C" void kernel_launch(void* const* d_in, const int* in_sizes, int n_in,
                              void* d_out, int out_size, void* d_ws, size_t ws_size,
                              hipStream_t stream) {
    const float* image = (const float*)d_in[0];
    const float* alpha = (const float*)d_in[1];
    const float* dct   = (const float*)d_in[2];
    float* outp = (float*)d_out;

    const int nblocks = in_sizes[0] / 64;
    const long long ntiles = ((long long)nblocks + BLKWG - 1) / BLKWG;
    int grid = (int)((ntiles < MAXWG) ? ntiles : MAXWG);
    if (grid < 1) grid = 1;

    dct8x8_kernel<<<grid, WG, 0, stream>>>(image, alpha, dct, outp, nblocks);
}

// Round 9
// 203.874 us; speedup vs baseline: 3.4579x; 3.4579x over previous
//
#include <hip/hip_runtime.h>

// Batched 8x8 iDCT: out = M^T * img * M + 128
//   M[i][j] = 0.5 * a[i] * cos((2j+1)*i*pi/16)
//   a[i]    = alpha[i*8+1]       (alpha = outer(a,a), a[1]==1)
//   cos term = dct[i*512 + j*8]  (dct_tensor[i,0,j,0]; cos(0)==1)
//
// Design I: row-per-lane, 4 blocks/thread, barrier-free, big register budget.
//   - lane owns one row of each of its 4 blocks; wave's 32 blocks are CONTIGUOUS
//     (8KB in / 8KB out per wave), every global instr coalesced (32B/lane stride)
//   - ALL 8 dwordx4 loads issued up front; __launch_bounds__(256,4) gives 128
//     VGPRs so the compiler can keep them in flight (R6/R8 post-mortem: the
//     (256,8) 64-VGPR cap caused spill/serialization -> FETCH/WRITE blowup)
//   - P-exchange intra-wave only (lane t writes block t>>3, same lanes read it)
//     -> no __syncthreads, just wave-local s_waitcnt lgkmcnt(0) (R8 proved correct)
//   - LDS stride 17 float4/block: balanced banks on write, broadcast on read
//   - plain stores (NT proven harmful R6); non-persistent sliding grid (proven)

#define WG      256
#define SETS    4
#define BLKWAVE 32                    // blocks per wave (SETS * 8)
#define BLKWG   128                   // blocks per WG (4 waves)
#define STRIDE4 17                    // float4 stride per block slot in LDS

template<bool FULL>
__device__ __forceinline__ void process_tile(
    const float4* __restrict__ in4, float4* __restrict__ o4,
    float4* __restrict__ lds4, const float* __restrict__ alpha,
    const float* __restrict__ dct, long long wgbase, int nblocks,
    int w, int b8, int r, int lane)
{
    const long long myblk0 = wgbase + w * BLKWAVE + b8;   // + s*8 per set

    // ---- issue ALL loads first (8 dwordx4 in flight per lane) ----
    float4 lo[SETS], hi[SETS];
#pragma unroll
    for (int s = 0; s < SETS; ++s) {
        const long long g = myblk0 + s * 8;
        if (FULL || g < nblocks) {
            const size_t p = (size_t)g * 16 + r * 2;
            lo[s] = in4[p];
            hi[s] = in4[p + 1];
        } else {
            lo[s] = make_float4(0.f, 0.f, 0.f, 0.f);
            hi[s] = lo[s];
        }
    }

    // ---- M -> SGPRs via readlane (overlaps the load latency) ----
    float mv;
    {
        const int i = lane >> 3, j = lane & 7;
        mv = 0.5f * alpha[i * 8 + 1] * dct[i * 512 + j * 8];
    }
    float M[64];
#pragma unroll
    for (int k = 0; k < 64; ++k)
        M[k] = __int_as_float(__builtin_amdgcn_readlane(__float_as_int(mv), k));

    // stage-2 weights M[x][r] (runtime r): per-lane loads, cache-hot
    float mu[8];
#pragma unroll
    for (int x = 0; x < 8; ++x)
        mu[x] = 0.5f * alpha[x * 8 + 1] * dct[x * 512 + r * 8];

    // ---- stage 1 per set: P[v] = sum_y row[y]*M[y][v] -> LDS slot ----
#pragma unroll
    for (int s = 0; s < SETS; ++s) {
        const float row[8] = {lo[s].x, lo[s].y, lo[s].z, lo[s].w,
                              hi[s].x, hi[s].y, hi[s].z, hi[s].w};
        float P[8];
#pragma unroll
        for (int v = 0; v < 8; ++v) {
            float acc = 0.0f;
#pragma unroll
            for (int y = 0; y < 8; ++y)
                acc = fmaf(row[y], M[y * 8 + v], acc);
            P[v] = acc;
        }
        float4* buf = &lds4[(w * BLKWAVE + s * 8 + b8) * STRIDE4];
        buf[r * 2 + 0] = make_float4(P[0], P[1], P[2], P[3]);
        buf[r * 2 + 1] = make_float4(P[4], P[5], P[6], P[7]);
    }

    // wave-local: my wave's ds_writes commit in order; exchange is intra-wave
    asm volatile("s_waitcnt lgkmcnt(0)" ::: "memory");

    // ---- stage 2 per set: O[v] = 128 + sum_x mu[x]*P[x][v]; store row ----
#pragma unroll
    for (int s = 0; s < SETS; ++s) {
        const float4* buf = &lds4[(w * BLKWAVE + s * 8 + b8) * STRIDE4];
        float O[8] = {128.f, 128.f, 128.f, 128.f, 128.f, 128.f, 128.f, 128.f};
#pragma unroll
        for (int x = 0; x < 8; ++x) {
            const float4 plo = buf[x * 2 + 0];
            const float4 phi = buf[x * 2 + 1];
            const float m = mu[x];
            O[0] = fmaf(m, plo.x, O[0]);
            O[1] = fmaf(m, plo.y, O[1]);
            O[2] = fmaf(m, plo.z, O[2]);
            O[3] = fmaf(m, plo.w, O[3]);
            O[4] = fmaf(m, phi.x, O[4]);
            O[5] = fmaf(m, phi.y, O[5]);
            O[6] = fmaf(m, phi.z, O[6]);
            O[7] = fmaf(m, phi.w, O[7]);
        }
        const long long g = myblk0 + s * 8;
        if (FULL || g < nblocks) {
            const size_t p = (size_t)g * 16 + r * 2;
            o4[p]     = make_float4(O[0], O[1], O[2], O[3]);
            o4[p + 1] = make_float4(O[4], O[5], O[6], O[7]);
        }
    }
}

__global__ __launch_bounds__(WG, 4) void dct8x8_kernel(
    const float* __restrict__ image,
    const float* __restrict__ alpha,
    const float* __restrict__ dct,
    float* __restrict__ out,
    int nblocks)
{
    __shared__ float4 lds4[BLKWG * STRIDE4];   // 128*17*16B = 34816B

    const int t = threadIdx.x;
    const int w = t >> 6;          // wave 0..3
    const int lane = t & 63;
    const int b8 = lane >> 3;      // block-within-wave-set 0..7
    const int r = lane & 7;        // my row

    const long long wgbase = (long long)blockIdx.x * BLKWG;
    const float4* in4 = (const float4*)image;
    float4* o4 = (float4*)out;

    if (wgbase + BLKWG <= (long long)nblocks) {
        process_tile<true >(in4, o4, lds4, alpha, dct, wgbase, nblocks, w, b8, r, lane);
    } else {
        process_tile<false>(in4, o4, lds4, alpha, dct, wgbase, nblocks, w, b8, r, lane);
    }
}

extern "C" void kernel_launch(void* const* d_in, const int* in_sizes, int n_in,
                              void* d_out, int out_size, void* d_ws, size_t ws_size,
                              hipStream_t stream) {
    const float* image = (const float*)d_in[0];
    const float* alpha = (const float*)d_in[1];
    const float* dct   = (const float*)d_in[2];
    float* outp = (float*)d_out;

    const int nblocks = in_sizes[0] / 64;
    const long long wgs = ((long long)nblocks + BLKWG - 1) / BLKWG;

    dct8x8_kernel<<<(int)wgs, WG, 0, stream>>>(image, alpha, dct, outp, nblocks);
}